// Round 7
// baseline (466.003 us; speedup 1.0000x reference)
//
#include <hip/hip_runtime.h>
#include <math.h>

// ---------------------------------------------------------------------------
// PermutedNetwork, R7.
// R6 counters: deform3 = 108us @ VALUBusy 22%, 4 FMA per ds_read_b128 (LDS
// pipe ~= FMA pipe), 2.25 blocks/CU. Fix: 2 px/thread (weight float4 feeds
// 2px x 4oc = 8 FMA), OC=8, NSPLIT 8 (L3) / 4 (L2). No launch_bounds on the
// deform kernels (R5 spill lesson; live set ~140 VGPR).
// Layout scheme (R5/R6-proven): gather inputs NHWC, outputs NCHW dense.
// ---------------------------------------------------------------------------

// ---- Layer 1: fused offset-conv + deform + relu, CIN=1. 2 pixels/thread.
__global__ void deform1_fused(const float* __restrict__ x,    // [64,96,96]
                              const float* __restrict__ woff, // [18,1,3,3]
                              const float* __restrict__ boff, // [18]
                              const float* __restrict__ w1,   // [16,1,3,3]
                              const float* __restrict__ b1,   // [16]
                              float* __restrict__ out) {      // [64,16,96,96]
  const int H = 96, W = 96, HW = H * W;
  __shared__ float wos[9 * 18];
  __shared__ __align__(16) float ws1[9 * 16];
  for (int t = threadIdx.x; t < 9 * 18; t += 256) { int k = t / 18, tc = t % 18; wos[t] = woff[tc * 9 + k]; }
  for (int t = threadIdx.x; t < 9 * 16; t += 256) { int k = t / 16, o = t % 16; ws1[t] = w1[o * 9 + k]; }
  __syncthreads();

  int gid = blockIdx.x * 256 + threadIdx.x;
  int p2 = gid % (HW / 2);
  int b  = gid / (HW / 2);
  int xi0 = (2 * p2) % W, yi = (2 * p2) / W;
  const float* xb = x + (size_t)b * HW;

  float v[3][4];
#pragma unroll
  for (int r = 0; r < 3; ++r) {
    int yy = yi + r - 1;
    float my = (yy >= 0 && yy < H) ? 1.f : 0.f;
    int cy = min(max(yy, 0), H - 1);
#pragma unroll
    for (int c = 0; c < 4; ++c) {
      int xx = xi0 + c - 1;
      float mx = (xx >= 0 && xx < W) ? 1.f : 0.f;
      int cx = min(max(xx, 0), W - 1);
      v[r][c] = xb[cy * W + cx] * (my * mx);
    }
  }

  float off0[18], off1[18];
#pragma unroll
  for (int tc = 0; tc < 18; ++tc) { float bb = boff[tc]; off0[tc] = bb; off1[tc] = bb; }
#pragma unroll
  for (int r = 0; r < 3; ++r)
#pragma unroll
    for (int c = 0; c < 3; ++c) {
      float t0 = v[r][c], t1 = v[r][c + 1];
      const float2* wv = (const float2*)&wos[(r * 3 + c) * 18];
#pragma unroll
      for (int tt = 0; tt < 9; ++tt) {
        float2 ww = wv[tt];
        off0[2 * tt]     = fmaf(ww.x, t0, off0[2 * tt]);
        off0[2 * tt + 1] = fmaf(ww.y, t0, off0[2 * tt + 1]);
        off1[2 * tt]     = fmaf(ww.x, t1, off1[2 * tt]);
        off1[2 * tt + 1] = fmaf(ww.y, t1, off1[2 * tt + 1]);
      }
    }

  float acc0[16], acc1[16];
#pragma unroll
  for (int o = 0; o < 16; ++o) { float bb = b1[o]; acc0[o] = bb; acc1[o] = bb; }

#pragma unroll
  for (int k = 0; k < 9; ++k) {
    int dky = k / 3 - 1, dkx = k % 3 - 1;
    float val0, val1;
    {
      float py = (float)(yi + dky) + off0[2 * k];
      float px = (float)(xi0 + dkx) + off0[2 * k + 1];
      float y0f = floorf(py), x0f = floorf(px);
      float fy = py - y0f, fx = px - x0f;
      int y0 = (int)y0f, x0 = (int)x0f, y1 = y0 + 1, x1 = x0 + 1;
      float vy0 = (y0 >= 0 && y0 < H) ? 1.f : 0.f;
      float vy1 = (y1 >= 0 && y1 < H) ? 1.f : 0.f;
      float vx0 = (x0 >= 0 && x0 < W) ? 1.f : 0.f;
      float vx1 = (x1 >= 0 && x1 < W) ? 1.f : 0.f;
      float w00 = (1.f - fy) * (1.f - fx) * vy0 * vx0;
      float w01 = (1.f - fy) * fx * vy0 * vx1;
      float w10 = fy * (1.f - fx) * vy1 * vx0;
      float w11 = fy * fx * vy1 * vx1;
      int cy0 = min(max(y0, 0), H - 1), cy1 = min(max(y1, 0), H - 1);
      int cx0 = min(max(x0, 0), W - 1), cx1 = min(max(x1, 0), W - 1);
      float a = xb[cy0 * W + cx0], bb = xb[cy0 * W + cx1];
      float c = xb[cy1 * W + cx0], d = xb[cy1 * W + cx1];
      val0 = w00 * a + w01 * bb + w10 * c + w11 * d;
    }
    {
      float py = (float)(yi + dky) + off1[2 * k];
      float px = (float)(xi0 + 1 + dkx) + off1[2 * k + 1];
      float y0f = floorf(py), x0f = floorf(px);
      float fy = py - y0f, fx = px - x0f;
      int y0 = (int)y0f, x0 = (int)x0f, y1 = y0 + 1, x1 = x0 + 1;
      float vy0 = (y0 >= 0 && y0 < H) ? 1.f : 0.f;
      float vy1 = (y1 >= 0 && y1 < H) ? 1.f : 0.f;
      float vx0 = (x0 >= 0 && x0 < W) ? 1.f : 0.f;
      float vx1 = (x1 >= 0 && x1 < W) ? 1.f : 0.f;
      float w00 = (1.f - fy) * (1.f - fx) * vy0 * vx0;
      float w01 = (1.f - fy) * fx * vy0 * vx1;
      float w10 = fy * (1.f - fx) * vy1 * vx0;
      float w11 = fy * fx * vy1 * vx1;
      int cy0 = min(max(y0, 0), H - 1), cy1 = min(max(y1, 0), H - 1);
      int cx0 = min(max(x0, 0), W - 1), cx1 = min(max(x1, 0), W - 1);
      float a = xb[cy0 * W + cx0], bb = xb[cy0 * W + cx1];
      float c = xb[cy1 * W + cx0], d = xb[cy1 * W + cx1];
      val1 = w00 * a + w01 * bb + w10 * c + w11 * d;
    }
    const float4* wv = (const float4*)&ws1[k * 16];
#pragma unroll
    for (int q = 0; q < 4; ++q) {
      float4 w4 = wv[q];
      acc0[4 * q + 0] = fmaf(w4.x, val0, acc0[4 * q + 0]);
      acc0[4 * q + 1] = fmaf(w4.y, val0, acc0[4 * q + 1]);
      acc0[4 * q + 2] = fmaf(w4.z, val0, acc0[4 * q + 2]);
      acc0[4 * q + 3] = fmaf(w4.w, val0, acc0[4 * q + 3]);
      acc1[4 * q + 0] = fmaf(w4.x, val1, acc1[4 * q + 0]);
      acc1[4 * q + 1] = fmaf(w4.y, val1, acc1[4 * q + 1]);
      acc1[4 * q + 2] = fmaf(w4.z, val1, acc1[4 * q + 2]);
      acc1[4 * q + 3] = fmaf(w4.w, val1, acc1[4 * q + 3]);
    }
  }

  float* op = out + (size_t)b * 16 * HW + (size_t)yi * W + xi0;
#pragma unroll
  for (int o = 0; o < 16; ++o) {
    float2 r = make_float2(fmaxf(acc0[o], 0.f), fmaxf(acc1[o], 0.f));
    *(float2*)(op + (size_t)o * HW) = r;
  }
}

// ---- 2x2 maxpool, NCHW in -> NHWC out.
template <int C, int HI>
__global__ void pool_nchw_to_nhwc(const float* __restrict__ in,  // [B,C,HI,HI]
                                  float* __restrict__ out) {     // [B,HO,HO,C]
  const int HO = HI / 2, C4 = C / 4;
  int gid = blockIdx.x * blockDim.x + threadIdx.x;
  if (gid >= 64 * HO * HO * C4) return;
  int c4 = gid % C4;
  int t = gid / C4;
  int x = t % HO; t /= HO;
  int y = t % HO;
  int b = t / HO;
  float4 r;
  float* rp = &r.x;
#pragma unroll
  for (int cc = 0; cc < 4; ++cc) {
    int c = c4 * 4 + cc;
    const float* p = in + ((size_t)(b * C + c) * HI + 2 * y) * HI + 2 * x;
    rp[cc] = fmaxf(fmaxf(p[0], p[1]), fmaxf(p[HI], p[HI + 1]));
  }
  *(float4*)(out + (((size_t)b * HO + y) * HO + x) * C + c4 * 4) = r;
}

// ---- 3x3 conv: NHWC in, NCHW out, no activation.
template <int CIN, int COUT, int NSPLIT>
__global__ __launch_bounds__(256, 4)
void conv3x3_hwc_chw(const float* __restrict__ in,  // [B,H,W,CIN]
                     const float* __restrict__ w,   // [COUT,CIN,3,3]
                     const float* __restrict__ bias,
                     float* __restrict__ out,       // [B,COUT,H,W]
                     int B, int H, int W) {
  constexpr int OC = COUT / NSPLIT;
  __shared__ float ws[9 * CIN * OC];
  int obase = blockIdx.y * OC;
  for (int t = threadIdx.x; t < 9 * CIN * OC; t += 256) {
    int k = t / (CIN * OC); int r = t % (CIN * OC);
    int c = r / OC; int o = r % OC;
    ws[t] = w[((obase + o) * CIN + c) * 9 + k];
  }
  __syncthreads();

  int gid = blockIdx.x * 256 + threadIdx.x;
  if (gid >= B * H * W) return;
  int x = gid % W; int t0 = gid / W; int y = t0 % H; int b = t0 / H;
  int HW = H * W;
  const float* inb = in + (size_t)b * HW * CIN;

  float acc[OC];
#pragma unroll
  for (int o = 0; o < OC; ++o) acc[o] = bias[obase + o];

#pragma unroll
  for (int ky = 0; ky < 3; ++ky) {
    int yy = y + ky - 1;
    if (yy < 0 || yy >= H) continue;
#pragma unroll
    for (int kx = 0; kx < 3; ++kx) {
      int xx = x + kx - 1;
      if (xx < 0 || xx >= W) continue;
      const float4* p4 = (const float4*)(inb + ((size_t)yy * W + xx) * CIN);
      int k = ky * 3 + kx;
#pragma unroll
      for (int c4 = 0; c4 < CIN / 4; ++c4) {
        float4 p = p4[c4];
        const float* pv = &p.x;
#pragma unroll
        for (int cc = 0; cc < 4; ++cc) {
          const float* wrow = &ws[(k * CIN + 4 * c4 + cc) * OC];
#pragma unroll
          for (int o = 0; o < OC; ++o) acc[o] = fmaf(wrow[o], pv[cc], acc[o]);
        }
      }
    }
  }

  float* op = out + (size_t)b * COUT * HW + (size_t)obase * HW + (size_t)y * W + x;
#pragma unroll
  for (int o = 0; o < OC; ++o) op[(size_t)o * HW] = acc[o];
}

// ---- Deformable 3x3 conv + ReLU, 2 px/thread: NHWC in, NCHW offsets/out.
// Weight float4 read feeds 2px x 4oc = 8 FMAs. No launch_bounds (spill risk).
template <int CIN, int COUT, int NSPLIT>
__global__ void deform2px(const float* __restrict__ in,     // [B,H,W,CIN]
                          const float* __restrict__ off_in, // [B,18,H,W]
                          const float* __restrict__ w,      // [COUT,CIN,3,3]
                          const float* __restrict__ bias,
                          float* __restrict__ out,          // [B,COUT,H,W]
                          int B, int H, int W) {
  constexpr int OC = COUT / NSPLIT;
  __shared__ __align__(16) float ws[9 * CIN * OC];
  int obase = blockIdx.y * OC;
  for (int t = threadIdx.x; t < 9 * CIN * OC; t += 256) {
    int k = t / (CIN * OC); int r = t % (CIN * OC);
    int c = r / OC; int o = r % OC;
    ws[t] = w[((obase + o) * CIN + c) * 9 + k];
  }
  __syncthreads();

  int gid = blockIdx.x * 256 + threadIdx.x;
  int HW = H * W, HW2 = HW / 2;
  if (gid >= B * HW2) return;
  int p2 = gid % HW2;
  int b  = gid / HW2;
  int xi0 = (2 * p2) % W, yi = (2 * p2) / W;   // pixels (yi,xi0), (yi,xi0+1)
  const float* inb = in + (size_t)b * HW * CIN;

  float off0[18], off1[18];
  const float* ofp = off_in + (size_t)b * 18 * HW + (size_t)yi * W + xi0;
#pragma unroll
  for (int tc = 0; tc < 18; ++tc) {
    float2 o2 = *(const float2*)(ofp + (size_t)tc * HW);
    off0[tc] = o2.x; off1[tc] = o2.y;
  }

  float acc0[OC], acc1[OC];
#pragma unroll
  for (int o = 0; o < OC; ++o) { float bb = bias[obase + o]; acc0[o] = bb; acc1[o] = bb; }

#pragma unroll
  for (int k = 0; k < 9; ++k) {
    int dky = k / 3 - 1, dkx = k % 3 - 1;
    // bilinear meta for both pixels
    float w000, w001, w010, w011, w100, w101, w110, w111;
    const float4 *pa0, *pb0, *pc0, *pd0, *pa1, *pb1, *pc1, *pd1;
    {
      float py = (float)(yi + dky) + off0[2 * k];
      float px = (float)(xi0 + dkx) + off0[2 * k + 1];
      float y0f = floorf(py), x0f = floorf(px);
      float fy = py - y0f, fx = px - x0f;
      int y0 = (int)y0f, x0 = (int)x0f, y1 = y0 + 1, x1 = x0 + 1;
      float vy0 = (y0 >= 0 && y0 < H) ? 1.f : 0.f;
      float vy1 = (y1 >= 0 && y1 < H) ? 1.f : 0.f;
      float vx0 = (x0 >= 0 && x0 < W) ? 1.f : 0.f;
      float vx1 = (x1 >= 0 && x1 < W) ? 1.f : 0.f;
      w000 = (1.f - fy) * (1.f - fx) * vy0 * vx0;
      w001 = (1.f - fy) * fx * vy0 * vx1;
      w010 = fy * (1.f - fx) * vy1 * vx0;
      w011 = fy * fx * vy1 * vx1;
      int cy0 = min(max(y0, 0), H - 1), cy1 = min(max(y1, 0), H - 1);
      int cx0 = min(max(x0, 0), W - 1), cx1 = min(max(x1, 0), W - 1);
      pa0 = (const float4*)(inb + ((size_t)cy0 * W + cx0) * CIN);
      pb0 = (const float4*)(inb + ((size_t)cy0 * W + cx1) * CIN);
      pc0 = (const float4*)(inb + ((size_t)cy1 * W + cx0) * CIN);
      pd0 = (const float4*)(inb + ((size_t)cy1 * W + cx1) * CIN);
    }
    {
      float py = (float)(yi + dky) + off1[2 * k];
      float px = (float)(xi0 + 1 + dkx) + off1[2 * k + 1];
      float y0f = floorf(py), x0f = floorf(px);
      float fy = py - y0f, fx = px - x0f;
      int y0 = (int)y0f, x0 = (int)x0f, y1 = y0 + 1, x1 = x0 + 1;
      float vy0 = (y0 >= 0 && y0 < H) ? 1.f : 0.f;
      float vy1 = (y1 >= 0 && y1 < H) ? 1.f : 0.f;
      float vx0 = (x0 >= 0 && x0 < W) ? 1.f : 0.f;
      float vx1 = (x1 >= 0 && x1 < W) ? 1.f : 0.f;
      w100 = (1.f - fy) * (1.f - fx) * vy0 * vx0;
      w101 = (1.f - fy) * fx * vy0 * vx1;
      w110 = fy * (1.f - fx) * vy1 * vx0;
      w111 = fy * fx * vy1 * vx1;
      int cy0 = min(max(y0, 0), H - 1), cy1 = min(max(y1, 0), H - 1);
      int cx0 = min(max(x0, 0), W - 1), cx1 = min(max(x1, 0), W - 1);
      pa1 = (const float4*)(inb + ((size_t)cy0 * W + cx0) * CIN);
      pb1 = (const float4*)(inb + ((size_t)cy0 * W + cx1) * CIN);
      pc1 = (const float4*)(inb + ((size_t)cy1 * W + cx0) * CIN);
      pd1 = (const float4*)(inb + ((size_t)cy1 * W + cx1) * CIN);
    }

#pragma unroll
    for (int c8 = 0; c8 < CIN / 8; ++c8) {
      // 16 independent float4 loads (2 quads x 4 corners x 2 px)
      float4 a00 = pa0[2 * c8], b00 = pb0[2 * c8], c00 = pc0[2 * c8], d00 = pd0[2 * c8];
      float4 a01 = pa0[2 * c8 + 1], b01 = pb0[2 * c8 + 1], c01 = pc0[2 * c8 + 1], d01 = pd0[2 * c8 + 1];
      float4 a10 = pa1[2 * c8], b10 = pb1[2 * c8], c10 = pc1[2 * c8], d10 = pd1[2 * c8];
      float4 a11 = pa1[2 * c8 + 1], b11 = pb1[2 * c8 + 1], c11 = pc1[2 * c8 + 1], d11 = pd1[2 * c8 + 1];
      float v0[8], v1[8];
      v0[0] = w000 * a00.x + w001 * b00.x + w010 * c00.x + w011 * d00.x;
      v0[1] = w000 * a00.y + w001 * b00.y + w010 * c00.y + w011 * d00.y;
      v0[2] = w000 * a00.z + w001 * b00.z + w010 * c00.z + w011 * d00.z;
      v0[3] = w000 * a00.w + w001 * b00.w + w010 * c00.w + w011 * d00.w;
      v0[4] = w000 * a01.x + w001 * b01.x + w010 * c01.x + w011 * d01.x;
      v0[5] = w000 * a01.y + w001 * b01.y + w010 * c01.y + w011 * d01.y;
      v0[6] = w000 * a01.z + w001 * b01.z + w010 * c01.z + w011 * d01.z;
      v0[7] = w000 * a01.w + w001 * b01.w + w010 * c01.w + w011 * d01.w;
      v1[0] = w100 * a10.x + w101 * b10.x + w110 * c10.x + w111 * d10.x;
      v1[1] = w100 * a10.y + w101 * b10.y + w110 * c10.y + w111 * d10.y;
      v1[2] = w100 * a10.z + w101 * b10.z + w110 * c10.z + w111 * d10.z;
      v1[3] = w100 * a10.w + w101 * b10.w + w110 * c10.w + w111 * d10.w;
      v1[4] = w100 * a11.x + w101 * b11.x + w110 * c11.x + w111 * d11.x;
      v1[5] = w100 * a11.y + w101 * b11.y + w110 * c11.y + w111 * d11.y;
      v1[6] = w100 * a11.z + w101 * b11.z + w110 * c11.z + w111 * d11.z;
      v1[7] = w100 * a11.w + w101 * b11.w + w110 * c11.w + w111 * d11.w;
#pragma unroll
      for (int cc = 0; cc < 8; ++cc) {
        const float4* wv = (const float4*)&ws[(k * CIN + 8 * c8 + cc) * OC];
#pragma unroll
        for (int q = 0; q < OC / 4; ++q) {
          float4 w4 = wv[q];
          acc0[4 * q + 0] = fmaf(w4.x, v0[cc], acc0[4 * q + 0]);
          acc0[4 * q + 1] = fmaf(w4.y, v0[cc], acc0[4 * q + 1]);
          acc0[4 * q + 2] = fmaf(w4.z, v0[cc], acc0[4 * q + 2]);
          acc0[4 * q + 3] = fmaf(w4.w, v0[cc], acc0[4 * q + 3]);
          acc1[4 * q + 0] = fmaf(w4.x, v1[cc], acc1[4 * q + 0]);
          acc1[4 * q + 1] = fmaf(w4.y, v1[cc], acc1[4 * q + 1]);
          acc1[4 * q + 2] = fmaf(w4.z, v1[cc], acc1[4 * q + 2]);
          acc1[4 * q + 3] = fmaf(w4.w, v1[cc], acc1[4 * q + 3]);
        }
      }
    }
  }

  float* op = out + (size_t)b * COUT * HW + (size_t)obase * HW + (size_t)yi * W + xi0;
#pragma unroll
  for (int o = 0; o < OC; ++o) {
    float2 r = make_float2(fmaxf(acc0[o], 0.f), fmaxf(acc1[o], 0.f));
    *(float2*)(op + (size_t)o * HW) = r;
  }
}

// ---- Adaptive avg pool 24->3 (8x8 bins) + fc(576->10), NCHW input.
__global__ void poolfc_kernel(const float* __restrict__ h,   // [B,64,24,24]
                              const float* __restrict__ wfc, // [10,576]
                              const float* __restrict__ bfc, // [10]
                              float* __restrict__ out) {     // [B,10]
  __shared__ float feat[576];
  int b = blockIdx.x;
  int f = threadIdx.x; // 576 threads
  int c = f / 9, ij = f % 9, i = ij / 3, j = ij % 3;
  const float* p = h + ((size_t)(b * 64 + c) * 24 + i * 8) * 24 + j * 8;
  float s = 0.f;
#pragma unroll
  for (int r = 0; r < 8; ++r)
#pragma unroll
    for (int q = 0; q < 8; ++q)
      s += p[r * 24 + q];
  feat[f] = s * (1.f / 64.f);
  __syncthreads();
  if (f < 10) {
    float acc = bfc[f];
    const float* wp = wfc + f * 576;
    for (int t = 0; t < 576; ++t) acc = fmaf(wp[t], feat[t], acc);
    out[b * 10 + f] = acc;
  }
}

extern "C" void kernel_launch(void* const* d_in, const int* in_sizes, int n_in,
                              void* d_out, int out_size, void* d_ws, size_t ws_size,
                              hipStream_t stream) {
  const float* x      = (const float*)d_in[0];
  const float* w_off1 = (const float*)d_in[1];
  const float* b_off1 = (const float*)d_in[2];
  const float* w1     = (const float*)d_in[3];
  const float* b1     = (const float*)d_in[4];
  const float* w_off2 = (const float*)d_in[5];
  const float* b_off2 = (const float*)d_in[6];
  const float* w2     = (const float*)d_in[7];
  const float* b2     = (const float*)d_in[8];
  const float* w_off3 = (const float*)d_in[9];
  const float* b_off3 = (const float*)d_in[10];
  const float* w3     = (const float*)d_in[11];
  const float* b3     = (const float*)d_in[12];
  const float* w_fc   = (const float*)d_in[13];
  const float* b_fc   = (const float*)d_in[14];
  float* out = (float*)d_out;

  char* ws = (char*)d_ws;
  float* A  = (float*)(ws);               // NCHW conv/deform outputs (<=37.75MB)
  float* Bp = (float*)(ws + 37748736);    // NHWC pooled inputs (<=9.44MB)
  float* Cp = (float*)(ws + 47185920);    // NCHW offsets (<=10.62MB)

  const int thr = 256;

  // Layer 1: fused offset+deform+relu -> A [64,16,96,96] NCHW (2 px/thread)
  deform1_fused<<<64 * 96 * 96 / 2 / thr, thr, 0, stream>>>(x, w_off1, b_off1, w1, b1, A);
  // pool -> Bp [64,48,48,16] NHWC
  {
    int total = 64 * 48 * 48 * 4;
    pool_nchw_to_nhwc<16, 96><<<(total + thr - 1) / thr, thr, 0, stream>>>(A, Bp);
  }

  // Layer 2: offset conv -> Cp [64,18,48,48] NCHW
  conv3x3_hwc_chw<16, 18, 1><<<dim3(576, 1), thr, 0, stream>>>(Bp, w_off2, b_off2, Cp, 64, 48, 48);
  // deform + relu -> A [64,32,48,48] NCHW  (2px/thread, OC=8, 288x4=1152 blocks)
  deform2px<16, 32, 4><<<dim3(64 * 48 * 48 / 2 / thr, 4), thr, 0, stream>>>(
      Bp, Cp, w2, b2, A, 64, 48, 48);
  // pool -> Bp [64,24,24,32] NHWC
  {
    int total = 64 * 24 * 24 * 8;
    pool_nchw_to_nhwc<32, 48><<<(total + thr - 1) / thr, thr, 0, stream>>>(A, Bp);
  }

  // Layer 3: offset conv -> Cp [64,18,24,24] NCHW   (NSPLIT=3)
  conv3x3_hwc_chw<32, 18, 3><<<dim3(144, 3), thr, 0, stream>>>(Bp, w_off3, b_off3, Cp, 64, 24, 24);
  // deform + relu -> A [64,64,24,24] NCHW  (2px/thread, OC=8, 72x8=576 blocks)
  deform2px<32, 64, 8><<<dim3(64 * 24 * 24 / 2 / thr, 8), thr, 0, stream>>>(
      Bp, Cp, w3, b3, A, 64, 24, 24);

  // avgpool(3x3) + fc -> out [64,10]
  poolfc_kernel<<<64, 576, 0, stream>>>(A, w_fc, b_fc, out);
}